// Round 11
// baseline (162.370 us; speedup 1.0000x reference)
//
#include <hip/hip_runtime.h>
#include <hip/hip_bf16.h>
#include <math.h>

typedef unsigned short u16;
typedef unsigned int   u32;
using bf16x8 = __attribute__((ext_vector_type(8))) short;   // 8 bf16 (4 VGPRs)
using f32x4  = __attribute__((ext_vector_type(4))) float;   // MFMA C/D frag
using f32x16 = __attribute__((ext_vector_type(16))) float;  // 32x32 C/D frag
using u32v4  = __attribute__((ext_vector_type(4))) u32;

#define TE 256
#define TH 8
#define TS 2048
#define TB 4
#define NTOK 8192
// (1/sqrt(32)) * log2(e): folded into Q so softmax is pure exp2
#define QSCALE 0.2550120651552454f
#define EXP2(x) __builtin_amdgcn_exp2f(x)

__device__ __forceinline__ void async16(const u16* g, u16* l) {
    __builtin_amdgcn_global_load_lds(
        (const __attribute__((address_space(1))) u32*)g,
        (__attribute__((address_space(3))) u32*)l, 16, 0, 0);
}
// pack 2 floats -> 2 bf16 (round-half-up): 2 adds + v_perm
__device__ __forceinline__ u32 pkbf(float a, float b) {
    u32 ua = __float_as_uint(a) + 0x8000u;
    u32 ub = __float_as_uint(b) + 0x8000u;
    return __builtin_amdgcn_perm(ub, ua, 0x07060302u);  // [ub.b3 ub.b2 ua.b3 ua.b2]
}
__device__ __forceinline__ u16 bf1(float a) {
    return (u16)((__float_as_uint(a) + 0x8000u) >> 16);
}

// ---------------- LayerNorm body: one wave per row, bf16 output ------------
__device__ __forceinline__ void ln_body(const float* __restrict__ in,
        u16* __restrict__ out, const float* __restrict__ gamma,
        const float* __restrict__ beta, int rowblk) {
    int row  = rowblk * 4 + (threadIdx.x >> 6);
    int lane = threadIdx.x & 63;
    float4 v = ((const float4*)(in + (size_t)row * TE))[lane];
    float s  = v.x + v.y + v.z + v.w;
    float s2 = v.x*v.x + v.y*v.y + v.z*v.z + v.w*v.w;
    #pragma unroll
    for (int off = 32; off > 0; off >>= 1) {
        s  += __shfl_down(s,  off, 64);
        s2 += __shfl_down(s2, off, 64);
    }
    s  = __shfl(s,  0, 64);
    s2 = __shfl(s2, 0, 64);
    float mu = s * (1.f / TE);
    float rs = rsqrtf(s2 * (1.f / TE) - mu * mu + 1e-5f);
    float4 g = ((const float4*)gamma)[lane];
    float4 b = ((const float4*)beta )[lane];
    u32 lo = pkbf((v.x - mu) * rs * g.x + b.x, (v.y - mu) * rs * g.y + b.y);
    u32 hi = pkbf((v.z - mu) * rs * g.z + b.z, (v.w - mu) * rs * g.w + b.w);
    ((uint2*)(out + (size_t)row * TE))[lane] = make_uint2(lo, hi);
}

// ---- prep: weight fp32->bf16 conversion (768 blocks) + LN1 (2048 blocks) ---
__global__ __launch_bounds__(256) void prep(const float* __restrict__ s0, u16* d0,
        const float* __restrict__ s1, u16* d1, const float* __restrict__ s2, u16* d2,
        const float* __restrict__ s3, u16* d3, const float* __restrict__ src,
        u16* __restrict__ xb, const float* __restrict__ g1,
        const float* __restrict__ be1) {
    if (blockIdx.x < 768) {
        int i = (blockIdx.x * 256 + threadIdx.x) * 4;
        const float* s; u16* d;
        if      (i < 196608) { s = s0; d = d0; }
        else if (i < 262144) { s = s1; d = d1; i -= 196608; }
        else if (i < 524288) { s = s2; d = d2; i -= 262144; }
        else                 { s = s3; d = d3; i -= 524288; }
        float4 v = *(const float4*)(s + i);
        *(uint2*)(d + i) = make_uint2(pkbf(v.x, v.y), pkbf(v.z, v.w));
    } else {
        ln_body(src, xb, g1, be1, blockIdx.x - 768);
    }
}

// ------------------- MFMA GEMM: C[N,M] = A[N,K] @ W[M,K]^T -----------------
// R2-proven structure: BK=64 staged as two 32-halves per barrier pair.
// BM=BN=128: 4 waves x (64tok x 64feat). BM=BN=64: 4 waves x (32tok x 32feat)
// Operands swapped (D rows=feat, cols=tok) -> lane holds 4 consecutive feats.
// EPI: 0=QKV: feat<256 -> Q bf16 [tok][256] (qscaled); 256..511 -> K frag-
// ordered [bh][tile][frag][hi][lq][8] (Kf = bias); >=512 -> V frag-ordered
// same layout (Vf = R).  2=bf16 relu(acc+bias); 3=fp32 acc+bias+residual.
template<int K, int BM, int EPI>
__global__ __launch_bounds__(256) void mgemm(const u16* __restrict__ A,
        const u16* __restrict__ W, const float* __restrict__ bias,
        const float* __restrict__ R, float* __restrict__ Cf,
        u16* __restrict__ Cb, int M) {
    constexpr int BN = BM;                       // square tiles
    __shared__ u16 Al[2][BM * 32];
    __shared__ u16 Wl[2][BN * 32];
    const int tid = threadIdx.x, w = tid >> 6, l = tid & 63;
    const int n0 = blockIdx.y * BM;              // token base
    const int m0 = blockIdx.x * BN;              // feat base
    constexpr int NT = (BM == 128) ? 4 : 2;      // tok frags / wave
    constexpr int NF = (BM == 128) ? 4 : 2;      // feat frags / wave
    const int tw = (w & 1) * NT * 16;
    const int fw = (w >> 1) * NF * 16;
    const int fr = l & 15, fq = l >> 4;
    const int sr = l >> 2, sc = (l & 3) * 8;
    f32x4 acc[NT][NF];
    #pragma unroll
    for (int t = 0; t < NT; t++)
        #pragma unroll
        for (int f = 0; f < NF; f++)
            #pragma unroll
            for (int r = 0; r < 4; r++) acc[t][f][r] = 0.f;

    for (int k0 = 0; k0 < K; k0 += 64) {
        __syncthreads();
        #pragma unroll
        for (int hh = 0; hh < 2; hh++) {
            const int kc = k0 + hh * 32;
            if (BM == 128) {
                #pragma unroll
                for (int c = 0; c < 2; c++) {
                    int rr = (w * 2 + c) * 16 + sr;
                    async16(A + (size_t)(n0 + rr) * K + kc + sc, &Al[hh][(w * 2 + c) * 512]);
                    async16(W + (size_t)(m0 + rr) * K + kc + sc, &Wl[hh][(w * 2 + c) * 512]);
                }
            } else {
                int rr = w * 16 + sr;
                async16(A + (size_t)(n0 + rr) * K + kc + sc, &Al[hh][w * 512]);
                async16(W + (size_t)(m0 + rr) * K + kc + sc, &Wl[hh][w * 512]);
            }
        }
        __syncthreads();
        #pragma unroll
        for (int hh = 0; hh < 2; hh++) {
            bf16x8 af[NT], wf[NF];
            #pragma unroll
            for (int t = 0; t < NT; t++)
                af[t] = *(const bf16x8*)&Al[hh][(tw + t * 16 + fr) * 32 + fq * 8];
            #pragma unroll
            for (int f = 0; f < NF; f++)
                wf[f] = *(const bf16x8*)&Wl[hh][(fw + f * 16 + fr) * 32 + fq * 8];
            #pragma unroll
            for (int t = 0; t < NT; t++)
                #pragma unroll
                for (int f = 0; f < NF; f++)
                    acc[t][f] = __builtin_amdgcn_mfma_f32_16x16x32_bf16(
                        wf[f], af[t], acc[t][f], 0, 0, 0);   // D rows=feat, cols=tok
        }
    }
    // epilogue: lane holds (tok = n0+tw+t*16+fr, feats fb..fb+3)
    #pragma unroll
    for (int t = 0; t < NT; t++) {
        const int tok = n0 + tw + t * 16 + fr;
        #pragma unroll
        for (int f = 0; f < NF; f++) {
            const int fb = m0 + fw + f * 16 + fq * 4;
            f32x4 v = acc[t][f];
            if (EPI == 0) {
                if (fb < 256) {
                    *(uint2*)(Cb + (size_t)tok * 256 + fb) = make_uint2(
                        pkbf(v[0]*QSCALE, v[1]*QSCALE), pkbf(v[2]*QSCALE, v[3]*QSCALE));
                } else if (fb < 512) {
                    // K fragment-ordered: [bh][tile][frag][hi][lq][8]
                    const int hh = (fb - 256) >> 5, dd = (fb - 256) & 31;
                    const int bh = (tok >> 11) * 8 + hh;
                    const int kv = tok & 2047, tile = kv >> 5, lq = kv & 31;
                    const int fg = dd >> 4, hg = (dd >> 3) & 1, j = dd & 7;
                    u16* kp = (u16*)bias +
                        (((((size_t)bh * 64 + tile) * 2 + fg) * 2 + hg) * 32 + lq) * 8 + j;
                    *(uint2*)kp = make_uint2(pkbf(v[0], v[1]), pkbf(v[2], v[3]));
                } else {
                    // V fragment-ordered: row = d, k-chunk = kv-within-tile
                    const int hh = (fb - 512) >> 5, dd = (fb - 512) & 31;
                    const int bh = (tok >> 11) * 8 + hh;
                    const int kv = tok & 2047, tile = kv >> 5, kvr = kv & 31;
                    const int fg = kvr >> 4, hg = (kvr >> 3) & 1, j = kvr & 7;
                    u16* vp = (u16*)R +
                        ((((size_t)bh * 64 + tile) * 2 + fg) * 2 + hg) * 256 +
                        (size_t)dd * 8 + j;
                    vp[0]  = bf1(v[0]);
                    vp[8]  = bf1(v[1]);
                    vp[16] = bf1(v[2]);
                    vp[24] = bf1(v[3]);
                }
            } else if (EPI == 2) {
                float4 b4 = *(const float4*)(bias + fb);
                *(uint2*)(Cb + (size_t)tok * M + fb) = make_uint2(
                    pkbf(fmaxf(v[0]+b4.x, 0.f), fmaxf(v[1]+b4.y, 0.f)),
                    pkbf(fmaxf(v[2]+b4.z, 0.f), fmaxf(v[3]+b4.w, 0.f)));
            } else {
                float4 b4 = *(const float4*)(bias + fb);
                float4 r4 = *(const float4*)(R + (size_t)tok * M + fb);
                *(float4*)(Cf + (size_t)tok * M + fb) = make_float4(
                    v[0]+b4.x+r4.x, v[1]+b4.y+r4.y, v[2]+b4.z+r4.z, v[3]+b4.w+r4.w);
            }
        }
    }
}

// ---- g4ln: out = src + attnb @ w_out^T, then x2b = LN2(out) (fused) -------
// Block = 32 tokens x all 256 feats (K=256), 8 waves: tg=w&1 (16 tok),
// fg=w>>1 (64 feats).  Epilogue owns complete rows -> LN computed in-block
// from an LDS fp32 tile (row pad 260 breaks bank aliasing).  Saves the
// separate LN2 kernel + its 12 MB round-trip.
__global__ __launch_bounds__(512) void g4ln(const u16* __restrict__ A,
        const u16* __restrict__ W, const float* __restrict__ src,
        float* __restrict__ out, u16* __restrict__ x2b,
        const float* __restrict__ g2, const float* __restrict__ be2) {
    __shared__ __align__(16) char smem[36864];
    u16* Al = (u16*)smem;                  // [2][32*32]
    u16* Wl = (u16*)(smem + 4096);         // [2][256*32]
    const int tid = threadIdx.x, w = tid >> 6, l = tid & 63;
    const int tg = w & 1, fg = w >> 1;
    const int fr = l & 15, fq = l >> 4;
    const int sr = l >> 2, sc = (l & 3) * 8;
    const int n0 = blockIdx.x * 32;
    f32x4 acc[4];
    #pragma unroll
    for (int f = 0; f < 4; f++)
        #pragma unroll
        for (int r = 0; r < 4; r++) acc[f][r] = 0.f;

    auto stage = [&](int st, int buf) {
        const int kc = st * 32;
        const int rr = w * 16 + sr;
        async16(W + (size_t)rr * 256 + kc + sc, &Wl[buf * 8192 + w * 512]);
        async16(W + (size_t)(rr + 128) * 256 + kc + sc, &Wl[buf * 8192 + 4096 + w * 512]);
        if (w < 2) async16(A + (size_t)(n0 + rr) * 256 + kc + sc, &Al[buf * 1024 + w * 512]);
    };

    stage(0, 0);
    __syncthreads();
    #pragma unroll 2
    for (int st = 0; st < 8; ++st) {
        const int buf = st & 1;
        if (st + 1 < 8) stage(st + 1, buf ^ 1);
        bf16x8 af = *(const bf16x8*)&Al[buf * 1024 + (tg * 16 + fr) * 32 + fq * 8];
        bf16x8 wf[4];
        #pragma unroll
        for (int f = 0; f < 4; f++)
            wf[f] = *(const bf16x8*)&Wl[buf * 8192 + (fg * 64 + f * 16 + fr) * 32 + fq * 8];
        #pragma unroll
        for (int f = 0; f < 4; f++)
            acc[f] = __builtin_amdgcn_mfma_f32_16x16x32_bf16(wf[f], af, acc[f], 0, 0, 0);
        __syncthreads();
    }
    // epilogue: residual add, write out, stash rows in LDS, then LN in-block
    float* T = (float*)smem;               // [32][260] f32 (33280 B <= 36864)
    const int tokl = tg * 16 + fr;
    const int tok  = n0 + tokl;
    #pragma unroll
    for (int f = 0; f < 4; ++f) {
        const int fb = fg * 64 + f * 16 + fq * 4;
        float4 s4 = *(const float4*)(src + (size_t)tok * 256 + fb);
        f32x4 v = acc[f];
        float4 o4 = make_float4(v[0]+s4.x, v[1]+s4.y, v[2]+s4.z, v[3]+s4.w);
        *(float4*)(out + (size_t)tok * 256 + fb) = o4;
        *(float4*)&T[tokl * 260 + fb] = o4;
    }
    __syncthreads();
    float4 gg = ((const float4*)g2)[l];
    float4 bb = ((const float4*)be2)[l];
    #pragma unroll
    for (int rr = 0; rr < 4; ++rr) {
        const int r = w * 4 + rr;
        float4 x = *(const float4*)&T[r * 260 + l * 4];
        float s  = x.x + x.y + x.z + x.w;
        float s2 = x.x*x.x + x.y*x.y + x.z*x.z + x.w*x.w;
        #pragma unroll
        for (int off = 32; off > 0; off >>= 1) {
            s  += __shfl_down(s,  off, 64);
            s2 += __shfl_down(s2, off, 64);
        }
        s  = __shfl(s,  0, 64);
        s2 = __shfl(s2, 0, 64);
        float mu = s * (1.f / 256.f);
        float rs = rsqrtf(s2 * (1.f / 256.f) - mu * mu + 1e-5f);
        u32 lo = pkbf((x.x - mu) * rs * gg.x + bb.x, (x.y - mu) * rs * gg.y + bb.y);
        u32 hi = pkbf((x.z - mu) * rs * gg.z + bb.z, (x.w - mu) * rs * gg.w + bb.w);
        *(uint2*)(x2b + (size_t)(n0 + r) * 256 + l * 4) = make_uint2(lo, hi);
    }
}

// ------------- MFMA flash attention, in-register softmax (T12) -------------
// L2-BW-bound fix: 64 q PER WAVE (two Q-frag sets A/B share every K/V load,
// halving L2 traffic 512->256 MB) x kv-split FOUR (kw = w = 0..3, 512 kv /
// 16 iters each).  Same grid (1024 blocks = 32 bh x 32 64-q tiles), same
// 16 waves/CU.  A/B softmax chains are independent -> extra ILP.  Depth-1
// register prefetch (BW-bound; frees 32 VGPR vs depth-2).
// Merge: kw>0 waves dump (oa, ob, psA, psB) to LDS (stride-35 f32 rows,
// conflict-free); kw=0 adds 3 partials + normalizes + stores both tiles.
// Block swizzle pins each (b,h) to one XCD.  __launch_bounds__(256,4)
// caps VGPR at 128 so occupancy stays grid-limited.
__global__ __launch_bounds__(256, 4) void attn_k(const u16* __restrict__ qb,
        const u16* __restrict__ kfb, const u16* __restrict__ vfb,
        u16* __restrict__ attn) {
    const int id = blockIdx.x;                 // 1024 blocks
    const int bh   = (id & 7) * 4 + (id >> 8); // xcd*4 + group
    const int tile = (id >> 3) & 31;           // 64-q tile within bh
    const int b = bh >> 3, h = bh & 7;
    const int tid = threadIdx.x, w = tid >> 6, l = tid & 63;
    const int lq = l & 31, hi = l >> 5;
    const size_t btok = (size_t)b * TS;
    const int q0 = tile * 64;

    __shared__ float mrg[3 * 64 * 35];         // 3 dump waves x 64 lanes x 35

    // Q frag sets: A = q0+lq, B = q0+32+lq  (B-op [col=q][k=d=hi*8..+8])
    const u16* qrowA = qb + (btok + q0 + lq) * 256 + h * 32 + hi * 8;
    bf16x8 qf0a = *(const bf16x8*)qrowA;
    bf16x8 qf1a = *(const bf16x8*)(qrowA + 16);
    const u16* qrowB = qrowA + 32 * 256;
    bf16x8 qf0b = *(const bf16x8*)qrowB;
    bf16x8 qf1b = *(const bf16x8*)(qrowB + 16);

    f32x16 zf, oa, ob;
    #pragma unroll
    for (int r = 0; r < 16; r++) { zf[r] = 0.f; oa[r] = 0.f; ob[r] = 0.f; }
    float psA = 0.f, psB = 0.f;

    // fragment streams: this wave's kv quarter = kw*512 kv (16 32-kv tiles)
    const u16* kp = kfb + ((size_t)bh * 64 + w * 16) * 1024 + l * 8;
    const u16* vp = vfb + ((size_t)bh * 64 + w * 16) * 1024 + l * 8;
    bf16x8 k0 = *(const bf16x8*)kp;
    bf16x8 k1 = *(const bf16x8*)(kp + 512);
    bf16x8 v0 = *(const bf16x8*)vp;
    bf16x8 v1 = *(const bf16x8*)(vp + 512);

    #pragma unroll 2
    for (int it = 0; it < 16; ++it) {
        kp += 1024; vp += 1024;
        // prefetch next tile (last iter reads past quarter end -> in-ws, unused)
        bf16x8 nk0 = *(const bf16x8*)kp;
        bf16x8 nk1 = *(const bf16x8*)(kp + 512);
        bf16x8 nv0 = *(const bf16x8*)vp;
        bf16x8 nv1 = *(const bf16x8*)(vp + 512);
        // S[kv][q] for both q-sets (independent chains; share k0/k1)
        f32x16 pA = __builtin_amdgcn_mfma_f32_32x32x16_bf16(k0, qf0a, zf, 0, 0, 0);
        f32x16 pB = __builtin_amdgcn_mfma_f32_32x32x16_bf16(k0, qf0b, zf, 0, 0, 0);
        pA = __builtin_amdgcn_mfma_f32_32x32x16_bf16(k1, qf1a, pA, 0, 0, 0);
        pB = __builtin_amdgcn_mfma_f32_32x32x16_bf16(k1, qf1b, pB, 0, 0, 0);
        float eA[16], eB[16];
        #pragma unroll
        for (int r = 0; r < 16; r++) { eA[r] = EXP2(pA[r]); eB[r] = EXP2(pB[r]); }
        psA += ((eA[0]+eA[1]) + (eA[2]+eA[3])) + ((eA[4]+eA[5]) + (eA[6]+eA[7]))
             + ((eA[8]+eA[9]) + (eA[10]+eA[11])) + ((eA[12]+eA[13]) + (eA[14]+eA[15]));
        psB += ((eB[0]+eB[1]) + (eB[2]+eB[3])) + ((eB[4]+eB[5]) + (eB[6]+eB[7]))
             + ((eB[8]+eB[9]) + (eB[10]+eB[11])) + ((eB[12]+eB[13]) + (eB[14]+eB[15]));
        u32 aA[8], aB[8];
        #pragma unroll
        for (int j = 0; j < 8; j++) {
            asm("v_cvt_pk_bf16_f32 %0, %1, %2"
                : "=v"(aA[j]) : "v"(eA[2*j]), "v"(eA[2*j+1]));
            asm("v_cvt_pk_bf16_f32 %0, %1, %2"
                : "=v"(aB[j]) : "v"(eB[2*j]), "v"(eB[2*j+1]));
        }
        asm("v_permlane32_swap_b32 %0, %1" : "+v"(aA[0]), "+v"(aA[2]));
        asm("v_permlane32_swap_b32 %0, %1" : "+v"(aA[1]), "+v"(aA[3]));
        asm("v_permlane32_swap_b32 %0, %1" : "+v"(aA[4]), "+v"(aA[6]));
        asm("v_permlane32_swap_b32 %0, %1" : "+v"(aA[5]), "+v"(aA[7]));
        asm("v_permlane32_swap_b32 %0, %1" : "+v"(aB[0]), "+v"(aB[2]));
        asm("v_permlane32_swap_b32 %0, %1" : "+v"(aB[1]), "+v"(aB[3]));
        asm("v_permlane32_swap_b32 %0, %1" : "+v"(aB[4]), "+v"(aB[6]));
        asm("v_permlane32_swap_b32 %0, %1" : "+v"(aB[5]), "+v"(aB[7]));
        u32v4 tA0 = {aA[0], aA[1], aA[2], aA[3]};
        u32v4 tA1 = {aA[4], aA[5], aA[6], aA[7]};
        u32v4 tB0 = {aB[0], aB[1], aB[2], aB[3]};
        u32v4 tB1 = {aB[4], aB[5], aB[6], aB[7]};
        bf16x8 pfA0 = __builtin_bit_cast(bf16x8, tA0);
        bf16x8 pfA1 = __builtin_bit_cast(bf16x8, tA1);
        bf16x8 pfB0 = __builtin_bit_cast(bf16x8, tB0);
        bf16x8 pfB1 = __builtin_bit_cast(bf16x8, tB1);
        // O^T += V^T * P^T for both q-sets (share v0/v1)
        oa = __builtin_amdgcn_mfma_f32_32x32x16_bf16(v0, pfA0, oa, 0, 0, 0);
        ob = __builtin_amdgcn_mfma_f32_32x32x16_bf16(v0, pfB0, ob, 0, 0, 0);
        oa = __builtin_amdgcn_mfma_f32_32x32x16_bf16(v1, pfA1, oa, 0, 0, 0);
        ob = __builtin_amdgcn_mfma_f32_32x32x16_bf16(v1, pfB1, ob, 0, 0, 0);
        k0 = nk0; k1 = nk1; v0 = nv0; v1 = nv1;
    }
    // lane l and l+32 (same q) cover complementary kv rows -> full quarter-sum
    psA += __shfl_xor(psA, 32, 64);
    psB += __shfl_xor(psB, 32, 64);

    // merge the four kv quarters: w>0 dump (oa, ob, psA, psB); w=0 adds+stores
    if (w > 0) {
        float* d = mrg + ((w - 1) * 64 + l) * 35;
        #pragma unroll
        for (int r = 0; r < 16; r++) { d[r] = oa[r]; d[16 + r] = ob[r]; }
        d[32] = psA; d[33] = psB;
    }
    __syncthreads();
    if (w == 0) {
        #pragma unroll
        for (int part = 0; part < 3; part++) {
            const float* d = mrg + (part * 64 + l) * 35;
            #pragma unroll
            for (int r = 0; r < 16; r++) { oa[r] += d[r]; ob[r] += d[16 + r]; }
            psA += d[32]; psB += d[33];
        }
        float invA = 1.f / psA, invB = 1.f / psB;
        // o reg r -> d = 8*(r>>2) + 4*hi + (r&3); q = lq
        int tokA = (int)btok + q0 + lq;
        u16* orowA = attn + (size_t)tokA * 256 + h * 32 + hi * 4;
        u16* orowB = orowA + 32 * 256;
        #pragma unroll
        for (int g = 0; g < 4; g++) {
            *(uint2*)(orowA + g * 8) = make_uint2(
                pkbf(oa[4*g]*invA, oa[4*g+1]*invA), pkbf(oa[4*g+2]*invA, oa[4*g+3]*invA));
            *(uint2*)(orowB + g * 8) = make_uint2(
                pkbf(ob[4*g]*invB, ob[4*g+1]*invB), pkbf(ob[4*g+2]*invB, ob[4*g+3]*invB));
        }
    }
}

extern "C" void kernel_launch(void* const* d_in, const int* in_sizes, int n_in,
                              void* d_out, int out_size, void* d_ws, size_t ws_size,
                              hipStream_t stream) {
    const float* src  = (const float*)d_in[0];
    const float* w_in = (const float*)d_in[1];
    const float* w_out= (const float*)d_in[2];
    const float* w1   = (const float*)d_in[3];
    const float* b1   = (const float*)d_in[4];
    const float* w2   = (const float*)d_in[5];
    const float* b2   = (const float*)d_in[6];
    const float* g1   = (const float*)d_in[7];
    const float* be1  = (const float*)d_in[8];
    const float* g2   = (const float*)d_in[9];
    const float* be2  = (const float*)d_in[10];
    float* out = (float*)d_out;

    u16* xb    = (u16*)d_ws;                       // [0, 4MB)    8192 x 256
    u16* qb    = xb + (size_t)NTOK * 256;          // [4, 8MB)    8192 x 256 Q
    u16* kfbuf = qb + (size_t)NTOK * 256;          // [8, 12MB)   K frags
    u16* vfbuf = kfbuf + (size_t)32 * 64 * 1024;   // [12, 16MB)  V frags
    u16* attnb = xb;                               // reuse (xb dead after G2)
    u16* h1b   = (u16*)d_ws;                       // 8192*1024 (after attn GEMMs)
    u16* x2b   = (u16*)((char*)d_ws + (size_t)NTOK * 1024 * 2);
    u16* wib   = x2b + (size_t)NTOK * 256;
    u16* wob   = wib + 768 * 256;
    u16* w1b   = wob + 256 * 256;
    u16* w2b   = w1b + 1024 * 256;

    // 1. weights -> bf16  +  xb = LN1(src) -> bf16   (one kernel)
    prep<<<768 + NTOK / 4, 256, 0, stream>>>(
        w_in, wib, w_out, wob, w1, w1b, w2, w2b, src, xb, g1, be1);
    // 2. qb = Q (scaled), kfbuf/vfbuf = K,V fragment-ordered  (= xb @ w_in^T)
    mgemm<256, 128, 0><<<dim3(6, 64), 256, 0, stream>>>(
        xb, wib, (const float*)kfbuf, (const float*)vfbuf, nullptr, qb, 768);
    // 3. attnb = flash-attention(qb, kfbuf, vfbuf)
    attn_k<<<dim3(1024), 256, 0, stream>>>(qb, kfbuf, vfbuf, attnb);
    // 4. out = src + attnb @ w_out^T (fp32)  +  x2b = LN2(out)   (fused)
    g4ln<<<256, 512, 0, stream>>>(attnb, wob, src, out, x2b, g2, be2);
    // 5. h1b = relu(x2b @ w1^T + b1) -> bf16
    mgemm<256, 128, 2><<<dim3(8, 64), 256, 0, stream>>>(
        x2b, w1b, b1, nullptr, nullptr, h1b, 1024);
    // 6. out = out + h1b @ w2^T + b2 (fp32)
    mgemm<1024, 64, 3><<<dim3(4, 128), 256, 0, stream>>>(
        h1b, w2b, b2, out, out, nullptr, 256);
}

// Round 12
// 160.575 us; speedup vs baseline: 1.0112x; 1.0112x over previous
//
#include <hip/hip_runtime.h>
#include <hip/hip_bf16.h>
#include <math.h>

typedef unsigned short u16;
typedef unsigned int   u32;
using bf16x8 = __attribute__((ext_vector_type(8))) short;   // 8 bf16 (4 VGPRs)
using f32x4  = __attribute__((ext_vector_type(4))) float;   // MFMA C/D frag
using f32x16 = __attribute__((ext_vector_type(16))) float;  // 32x32 C/D frag
using u32v4  = __attribute__((ext_vector_type(4))) u32;

#define TE 256
#define TH 8
#define TS 2048
#define TB 4
#define NTOK 8192
// (1/sqrt(32)) * log2(e): folded into Q so softmax is pure exp2
#define QSCALE 0.2550120651552454f
#define EXP2(x) __builtin_amdgcn_exp2f(x)

__device__ __forceinline__ void async16(const u16* g, u16* l) {
    __builtin_amdgcn_global_load_lds(
        (const __attribute__((address_space(1))) u32*)g,
        (__attribute__((address_space(3))) u32*)l, 16, 0, 0);
}
// pack 2 floats -> 2 bf16 (round-half-up): 2 adds + v_perm
__device__ __forceinline__ u32 pkbf(float a, float b) {
    u32 ua = __float_as_uint(a) + 0x8000u;
    u32 ub = __float_as_uint(b) + 0x8000u;
    return __builtin_amdgcn_perm(ub, ua, 0x07060302u);  // [ub.b3 ub.b2 ua.b3 ua.b2]
}
__device__ __forceinline__ u16 bf1(float a) {
    return (u16)((__float_as_uint(a) + 0x8000u) >> 16);
}

// ---------------- LayerNorm body: one wave per row, bf16 output ------------
__device__ __forceinline__ void ln_body(const float* __restrict__ in,
        u16* __restrict__ out, const float* __restrict__ gamma,
        const float* __restrict__ beta, int rowblk) {
    int row  = rowblk * 4 + (threadIdx.x >> 6);
    int lane = threadIdx.x & 63;
    float4 v = ((const float4*)(in + (size_t)row * TE))[lane];
    float s  = v.x + v.y + v.z + v.w;
    float s2 = v.x*v.x + v.y*v.y + v.z*v.z + v.w*v.w;
    #pragma unroll
    for (int off = 32; off > 0; off >>= 1) {
        s  += __shfl_down(s,  off, 64);
        s2 += __shfl_down(s2, off, 64);
    }
    s  = __shfl(s,  0, 64);
    s2 = __shfl(s2, 0, 64);
    float mu = s * (1.f / TE);
    float rs = rsqrtf(s2 * (1.f / TE) - mu * mu + 1e-5f);
    float4 g = ((const float4*)gamma)[lane];
    float4 b = ((const float4*)beta )[lane];
    u32 lo = pkbf((v.x - mu) * rs * g.x + b.x, (v.y - mu) * rs * g.y + b.y);
    u32 hi = pkbf((v.z - mu) * rs * g.z + b.z, (v.w - mu) * rs * g.w + b.w);
    ((uint2*)(out + (size_t)row * TE))[lane] = make_uint2(lo, hi);
}

// ---- prep: weight fp32->bf16 conversion (768 blocks) + LN1 (2048 blocks) ---
__global__ __launch_bounds__(256) void prep(const float* __restrict__ s0, u16* d0,
        const float* __restrict__ s1, u16* d1, const float* __restrict__ s2, u16* d2,
        const float* __restrict__ s3, u16* d3, const float* __restrict__ src,
        u16* __restrict__ xb, const float* __restrict__ g1,
        const float* __restrict__ be1) {
    if (blockIdx.x < 768) {
        int i = (blockIdx.x * 256 + threadIdx.x) * 4;
        const float* s; u16* d;
        if      (i < 196608) { s = s0; d = d0; }
        else if (i < 262144) { s = s1; d = d1; i -= 196608; }
        else if (i < 524288) { s = s2; d = d2; i -= 262144; }
        else                 { s = s3; d = d3; i -= 524288; }
        float4 v = *(const float4*)(s + i);
        *(uint2*)(d + i) = make_uint2(pkbf(v.x, v.y), pkbf(v.z, v.w));
    } else {
        ln_body(src, xb, g1, be1, blockIdx.x - 768);
    }
}

// ------------------- MFMA GEMM: C[N,M] = A[N,K] @ W[M,K]^T -----------------
// R2-proven structure: BK=64 staged as two 32-halves per barrier pair.
// BM=BN=128: 4 waves x (64tok x 64feat). BM=BN=64: 4 waves x (32tok x 32feat)
// Operands swapped (D rows=feat, cols=tok) -> lane holds 4 consecutive feats.
// EPI: 0=QKV: feat<256 -> Q bf16 [tok][256] (qscaled); 256..511 -> K frag-
// ordered [bh][tile][frag][hi][lq][8] (Kf = bias); >=512 -> V frag-ordered
// same layout (Vf = R).  2=bf16 relu(acc+bias); 3=fp32 acc+bias+residual.
template<int K, int BM, int EPI>
__global__ __launch_bounds__(256) void mgemm(const u16* __restrict__ A,
        const u16* __restrict__ W, const float* __restrict__ bias,
        const float* __restrict__ R, float* __restrict__ Cf,
        u16* __restrict__ Cb, int M) {
    constexpr int BN = BM;                       // square tiles
    __shared__ u16 Al[2][BM * 32];
    __shared__ u16 Wl[2][BN * 32];
    const int tid = threadIdx.x, w = tid >> 6, l = tid & 63;
    const int n0 = blockIdx.y * BM;              // token base
    const int m0 = blockIdx.x * BN;              // feat base
    constexpr int NT = (BM == 128) ? 4 : 2;      // tok frags / wave
    constexpr int NF = (BM == 128) ? 4 : 2;      // feat frags / wave
    const int tw = (w & 1) * NT * 16;
    const int fw = (w >> 1) * NF * 16;
    const int fr = l & 15, fq = l >> 4;
    const int sr = l >> 2, sc = (l & 3) * 8;
    f32x4 acc[NT][NF];
    #pragma unroll
    for (int t = 0; t < NT; t++)
        #pragma unroll
        for (int f = 0; f < NF; f++)
            #pragma unroll
            for (int r = 0; r < 4; r++) acc[t][f][r] = 0.f;

    for (int k0 = 0; k0 < K; k0 += 64) {
        __syncthreads();
        #pragma unroll
        for (int hh = 0; hh < 2; hh++) {
            const int kc = k0 + hh * 32;
            if (BM == 128) {
                #pragma unroll
                for (int c = 0; c < 2; c++) {
                    int rr = (w * 2 + c) * 16 + sr;
                    async16(A + (size_t)(n0 + rr) * K + kc + sc, &Al[hh][(w * 2 + c) * 512]);
                    async16(W + (size_t)(m0 + rr) * K + kc + sc, &Wl[hh][(w * 2 + c) * 512]);
                }
            } else {
                int rr = w * 16 + sr;
                async16(A + (size_t)(n0 + rr) * K + kc + sc, &Al[hh][w * 512]);
                async16(W + (size_t)(m0 + rr) * K + kc + sc, &Wl[hh][w * 512]);
            }
        }
        __syncthreads();
        #pragma unroll
        for (int hh = 0; hh < 2; hh++) {
            bf16x8 af[NT], wf[NF];
            #pragma unroll
            for (int t = 0; t < NT; t++)
                af[t] = *(const bf16x8*)&Al[hh][(tw + t * 16 + fr) * 32 + fq * 8];
            #pragma unroll
            for (int f = 0; f < NF; f++)
                wf[f] = *(const bf16x8*)&Wl[hh][(fw + f * 16 + fr) * 32 + fq * 8];
            #pragma unroll
            for (int t = 0; t < NT; t++)
                #pragma unroll
                for (int f = 0; f < NF; f++)
                    acc[t][f] = __builtin_amdgcn_mfma_f32_16x16x32_bf16(
                        wf[f], af[t], acc[t][f], 0, 0, 0);   // D rows=feat, cols=tok
        }
    }
    // epilogue: lane holds (tok = n0+tw+t*16+fr, feats fb..fb+3)
    #pragma unroll
    for (int t = 0; t < NT; t++) {
        const int tok = n0 + tw + t * 16 + fr;
        #pragma unroll
        for (int f = 0; f < NF; f++) {
            const int fb = m0 + fw + f * 16 + fq * 4;
            f32x4 v = acc[t][f];
            if (EPI == 0) {
                if (fb < 256) {
                    *(uint2*)(Cb + (size_t)tok * 256 + fb) = make_uint2(
                        pkbf(v[0]*QSCALE, v[1]*QSCALE), pkbf(v[2]*QSCALE, v[3]*QSCALE));
                } else if (fb < 512) {
                    // K fragment-ordered: [bh][tile][frag][hi][lq][8]
                    const int hh = (fb - 256) >> 5, dd = (fb - 256) & 31;
                    const int bh = (tok >> 11) * 8 + hh;
                    const int kv = tok & 2047, tile = kv >> 5, lq = kv & 31;
                    const int fg = dd >> 4, hg = (dd >> 3) & 1, j = dd & 7;
                    u16* kp = (u16*)bias +
                        (((((size_t)bh * 64 + tile) * 2 + fg) * 2 + hg) * 32 + lq) * 8 + j;
                    *(uint2*)kp = make_uint2(pkbf(v[0], v[1]), pkbf(v[2], v[3]));
                } else {
                    // V fragment-ordered: row = d, k-chunk = kv-within-tile
                    const int hh = (fb - 512) >> 5, dd = (fb - 512) & 31;
                    const int bh = (tok >> 11) * 8 + hh;
                    const int kv = tok & 2047, tile = kv >> 5, kvr = kv & 31;
                    const int fg = kvr >> 4, hg = (kvr >> 3) & 1, j = kvr & 7;
                    u16* vp = (u16*)R +
                        ((((size_t)bh * 64 + tile) * 2 + fg) * 2 + hg) * 256 +
                        (size_t)dd * 8 + j;
                    vp[0]  = bf1(v[0]);
                    vp[8]  = bf1(v[1]);
                    vp[16] = bf1(v[2]);
                    vp[24] = bf1(v[3]);
                }
            } else if (EPI == 2) {
                float4 b4 = *(const float4*)(bias + fb);
                *(uint2*)(Cb + (size_t)tok * M + fb) = make_uint2(
                    pkbf(fmaxf(v[0]+b4.x, 0.f), fmaxf(v[1]+b4.y, 0.f)),
                    pkbf(fmaxf(v[2]+b4.z, 0.f), fmaxf(v[3]+b4.w, 0.f)));
            } else {
                float4 b4 = *(const float4*)(bias + fb);
                float4 r4 = *(const float4*)(R + (size_t)tok * M + fb);
                *(float4*)(Cf + (size_t)tok * M + fb) = make_float4(
                    v[0]+b4.x+r4.x, v[1]+b4.y+r4.y, v[2]+b4.z+r4.z, v[3]+b4.w+r4.w);
            }
        }
    }
}

// ---- g4ln: out = src + attnb @ w_out^T, then x2b = LN2(out) (fused) -------
// Block = 32 tokens x all 256 feats (K=256), 8 waves: tg=w&1 (16 tok),
// fg=w>>1 (64 feats).  Epilogue owns complete rows -> LN computed in-block
// from an LDS fp32 tile (row pad 260 breaks bank aliasing).  Saves the
// separate LN2 kernel + its 12 MB round-trip.
__global__ __launch_bounds__(512) void g4ln(const u16* __restrict__ A,
        const u16* __restrict__ W, const float* __restrict__ src,
        float* __restrict__ out, u16* __restrict__ x2b,
        const float* __restrict__ g2, const float* __restrict__ be2) {
    __shared__ __align__(16) char smem[36864];
    u16* Al = (u16*)smem;                  // [2][32*32]
    u16* Wl = (u16*)(smem + 4096);         // [2][256*32]
    const int tid = threadIdx.x, w = tid >> 6, l = tid & 63;
    const int tg = w & 1, fg = w >> 1;
    const int fr = l & 15, fq = l >> 4;
    const int sr = l >> 2, sc = (l & 3) * 8;
    const int n0 = blockIdx.x * 32;
    f32x4 acc[4];
    #pragma unroll
    for (int f = 0; f < 4; f++)
        #pragma unroll
        for (int r = 0; r < 4; r++) acc[f][r] = 0.f;

    auto stage = [&](int st, int buf) {
        const int kc = st * 32;
        const int rr = w * 16 + sr;
        async16(W + (size_t)rr * 256 + kc + sc, &Wl[buf * 8192 + w * 512]);
        async16(W + (size_t)(rr + 128) * 256 + kc + sc, &Wl[buf * 8192 + 4096 + w * 512]);
        if (w < 2) async16(A + (size_t)(n0 + rr) * 256 + kc + sc, &Al[buf * 1024 + w * 512]);
    };

    stage(0, 0);
    __syncthreads();
    #pragma unroll 2
    for (int st = 0; st < 8; ++st) {
        const int buf = st & 1;
        if (st + 1 < 8) stage(st + 1, buf ^ 1);
        bf16x8 af = *(const bf16x8*)&Al[buf * 1024 + (tg * 16 + fr) * 32 + fq * 8];
        bf16x8 wf[4];
        #pragma unroll
        for (int f = 0; f < 4; f++)
            wf[f] = *(const bf16x8*)&Wl[buf * 8192 + (fg * 64 + f * 16 + fr) * 32 + fq * 8];
        #pragma unroll
        for (int f = 0; f < 4; f++)
            acc[f] = __builtin_amdgcn_mfma_f32_16x16x32_bf16(wf[f], af, acc[f], 0, 0, 0);
        __syncthreads();
    }
    // epilogue: residual add, write out, stash rows in LDS, then LN in-block
    float* T = (float*)smem;               // [32][260] f32 (33280 B <= 36864)
    const int tokl = tg * 16 + fr;
    const int tok  = n0 + tokl;
    #pragma unroll
    for (int f = 0; f < 4; ++f) {
        const int fb = fg * 64 + f * 16 + fq * 4;
        float4 s4 = *(const float4*)(src + (size_t)tok * 256 + fb);
        f32x4 v = acc[f];
        float4 o4 = make_float4(v[0]+s4.x, v[1]+s4.y, v[2]+s4.z, v[3]+s4.w);
        *(float4*)(out + (size_t)tok * 256 + fb) = o4;
        *(float4*)&T[tokl * 260 + fb] = o4;
    }
    __syncthreads();
    float4 gg = ((const float4*)g2)[l];
    float4 bb = ((const float4*)be2)[l];
    #pragma unroll
    for (int rr = 0; rr < 4; ++rr) {
        const int r = w * 4 + rr;
        float4 x = *(const float4*)&T[r * 260 + l * 4];
        float s  = x.x + x.y + x.z + x.w;
        float s2 = x.x*x.x + x.y*x.y + x.z*x.z + x.w*x.w;
        #pragma unroll
        for (int off = 32; off > 0; off >>= 1) {
            s  += __shfl_down(s,  off, 64);
            s2 += __shfl_down(s2, off, 64);
        }
        s  = __shfl(s,  0, 64);
        s2 = __shfl(s2, 0, 64);
        float mu = s * (1.f / 256.f);
        float rs = rsqrtf(s2 * (1.f / 256.f) - mu * mu + 1e-5f);
        u32 lo = pkbf((x.x - mu) * rs * gg.x + bb.x, (x.y - mu) * rs * gg.y + bb.y);
        u32 hi = pkbf((x.z - mu) * rs * gg.z + bb.z, (x.w - mu) * rs * gg.w + bb.w);
        *(uint2*)(x2b + (size_t)(n0 + r) * 256 + l * 4) = make_uint2(lo, hi);
    }
}

// ------------- MFMA flash attention, in-register softmax (T12) -------------
// 32x32x16 MFMAs, swapped QK^T (mfma(K,Q)): lane (col=q=l&31) holds 16 P
// values.  P -> bf16 PV-fragment fully in-register (cvt_pk + permlane32).
// K/V pre-fragmented in global (QKV-GEMM epilogue) -> 1KB coalesced wave
// loads.  DEPTH-2 register prefetch: loads for tile i+2 are issued before
// computing tile i (~360cy of cover > ~250cy L2 latency).  Four named
// K/V register sets (a/b live, c/d in flight) -- no runtime-indexed arrays
// (rule #20).  kv-split 2: waves (qw=w&1, kw=w>>1); partials merge by
// addition in LDS.  Block swizzle pins each (b,h) to one XCD.
__global__ __launch_bounds__(256, 4) void attn_k(const u16* __restrict__ qb,
        const u16* __restrict__ kfb, const u16* __restrict__ vfb,
        u16* __restrict__ attn) {
    const int id = blockIdx.x;                 // 1024 blocks
    const int bh   = (id & 7) * 4 + (id >> 8); // xcd*4 + group
    const int tile = (id >> 3) & 31;           // 64-q tile within bh
    const int b = bh >> 3, h = bh & 7;
    const int tid = threadIdx.x, w = tid >> 6, l = tid & 63;
    const int qw = w & 1, kw = w >> 1;
    const int lq = l & 31, hi = l >> 5;
    const size_t btok = (size_t)b * TS;
    const int q0 = tile * 64 + qw * 32;

    __shared__ float mrg[2304];                // 2 x 64 lanes x 18 f32

    // Q frags: B-op [col=q=l&31][k=d=(l>>5)*8..+8], pre-scaled by QSCALE
    const u16* qrow = qb + (btok + q0 + lq) * 256 + h * 32 + hi * 8;
    bf16x8 qf0 = *(const bf16x8*)qrow;         // d 0..16
    bf16x8 qf1 = *(const bf16x8*)(qrow + 16);  // d 16..32

    f32x16 zf, o;
    #pragma unroll
    for (int r = 0; r < 16; r++) { zf[r] = 0.f; o[r] = 0.f; }
    float ps = 0.f;

    // fragment streams: 1024 u16 per 32-kv tile, lane l owns bytes l*16..+16
    const u16* kp = kfb + ((size_t)bh * 64 + kw * 32) * 1024 + l * 8;
    const u16* vp = vfb + ((size_t)bh * 64 + kw * 32) * 1024 + l * 8;

    // per-32kv-tile compute: QK^T -> exp2 -> pack -> permlane -> PV
    auto body = [&](bf16x8 k0, bf16x8 k1, bf16x8 v0, bf16x8 v1) {
        f32x16 p = __builtin_amdgcn_mfma_f32_32x32x16_bf16(k0, qf0, zf, 0, 0, 0);
        p = __builtin_amdgcn_mfma_f32_32x32x16_bf16(k1, qf1, p, 0, 0, 0);
        float e[16];
        #pragma unroll
        for (int r = 0; r < 16; r++) e[r] = EXP2(p[r]);
        ps += ((e[0]+e[1]) + (e[2]+e[3])) + ((e[4]+e[5]) + (e[6]+e[7]))
            + ((e[8]+e[9]) + (e[10]+e[11])) + ((e[12]+e[13]) + (e[14]+e[15]));
        u32 a[8];
        #pragma unroll
        for (int j = 0; j < 8; j++)
            asm("v_cvt_pk_bf16_f32 %0, %1, %2"
                : "=v"(a[j]) : "v"(e[2*j]), "v"(e[2*j+1]));
        asm("v_permlane32_swap_b32 %0, %1" : "+v"(a[0]), "+v"(a[2]));
        asm("v_permlane32_swap_b32 %0, %1" : "+v"(a[1]), "+v"(a[3]));
        asm("v_permlane32_swap_b32 %0, %1" : "+v"(a[4]), "+v"(a[6]));
        asm("v_permlane32_swap_b32 %0, %1" : "+v"(a[5]), "+v"(a[7]));
        u32v4 t0 = {a[0], a[1], a[2], a[3]};   // P^T[q][kv0+hi*8 .. +8]
        u32v4 t1 = {a[4], a[5], a[6], a[7]};   // P^T[q][kv0+16+hi*8 .. +8]
        bf16x8 pf0 = __builtin_bit_cast(bf16x8, t0);
        bf16x8 pf1 = __builtin_bit_cast(bf16x8, t1);
        o = __builtin_amdgcn_mfma_f32_32x32x16_bf16(v0, pf0, o, 0, 0, 0);
        o = __builtin_amdgcn_mfma_f32_32x32x16_bf16(v1, pf1, o, 0, 0, 0);
    };

    // depth-2 pipeline: a/b = tiles i, i+1 (live); c/d = tiles i+2, i+3
    bf16x8 ak0 = *(const bf16x8*)(kp);
    bf16x8 ak1 = *(const bf16x8*)(kp + 512);
    bf16x8 av0 = *(const bf16x8*)(vp);
    bf16x8 av1 = *(const bf16x8*)(vp + 512);
    bf16x8 bk0 = *(const bf16x8*)(kp + 1024);
    bf16x8 bk1 = *(const bf16x8*)(kp + 1536);
    bf16x8 bv0 = *(const bf16x8*)(vp + 1024);
    bf16x8 bv1 = *(const bf16x8*)(vp + 1536);
    u32 off = 2048;
    for (int it = 0; it < 32; it += 2) {
        // issue tile i+2 (last pair reads past end -> in-ws, unused)
        bf16x8 ck0 = *(const bf16x8*)(kp + off);
        bf16x8 ck1 = *(const bf16x8*)(kp + off + 512);
        bf16x8 cv0 = *(const bf16x8*)(vp + off);
        bf16x8 cv1 = *(const bf16x8*)(vp + off + 512);
        body(ak0, ak1, av0, av1);
        // issue tile i+3
        bf16x8 dk0 = *(const bf16x8*)(kp + off + 1024);
        bf16x8 dk1 = *(const bf16x8*)(kp + off + 1536);
        bf16x8 dv0 = *(const bf16x8*)(vp + off + 1024);
        bf16x8 dv1 = *(const bf16x8*)(vp + off + 1536);
        body(bk0, bk1, bv0, bv1);
        ak0 = ck0; ak1 = ck1; av0 = cv0; av1 = cv1;
        bk0 = dk0; bk1 = dk1; bv0 = dv0; bv1 = dv1;
        off += 2048;
    }
    // lane l and l+32 (same q) cover complementary kv rows -> full half-sum
    ps += __shfl_xor(ps, 32, 64);

    // merge the two kv halves: kw=1 dumps (o, ps); kw=0 adds + stores
    if (kw == 1) {
        float* d = mrg + (qw * 64 + l) * 18;
        #pragma unroll
        for (int r = 0; r < 16; r++) d[r] = o[r];
        d[16] = ps;
    }
    __syncthreads();
    if (kw == 0) {
        const float* d = mrg + (qw * 64 + l) * 18;
        #pragma unroll
        for (int r = 0; r < 16; r++) o[r] += d[r];
        ps += d[16];
        float inv = 1.f / ps;
        // o reg r -> d = 8*(r>>2) + 4*hi + (r&3); q = lq
        int tok = (int)btok + q0 + lq;
        u16* orow = attn + (size_t)tok * 256 + h * 32 + hi * 4;
        #pragma unroll
        for (int g = 0; g < 4; g++)
            *(uint2*)(orow + g * 8) = make_uint2(
                pkbf(o[4*g]*inv, o[4*g+1]*inv), pkbf(o[4*g+2]*inv, o[4*g+3]*inv));
    }
}

extern "C" void kernel_launch(void* const* d_in, const int* in_sizes, int n_in,
                              void* d_out, int out_size, void* d_ws, size_t ws_size,
                              hipStream_t stream) {
    const float* src  = (const float*)d_in[0];
    const float* w_in = (const float*)d_in[1];
    const float* w_out= (const float*)d_in[2];
    const float* w1   = (const float*)d_in[3];
    const float* b1   = (const float*)d_in[4];
    const float* w2   = (const float*)d_in[5];
    const float* b2   = (const float*)d_in[6];
    const float* g1   = (const float*)d_in[7];
    const float* be1  = (const float*)d_in[8];
    const float* g2   = (const float*)d_in[9];
    const float* be2  = (const float*)d_in[10];
    float* out = (float*)d_out;

    u16* xb    = (u16*)d_ws;                       // [0, 4MB)    8192 x 256
    u16* qb    = xb + (size_t)NTOK * 256;          // [4, 8MB)    8192 x 256 Q
    u16* kfbuf = qb + (size_t)NTOK * 256;          // [8, 12MB)   K frags
    u16* vfbuf = kfbuf + (size_t)32 * 64 * 1024;   // [12, 16MB)  V frags
    u16* attnb = xb;                               // reuse (xb dead after G2)
    u16* h1b   = (u16*)d_ws;                       // 8192*1024 (after attn GEMMs)
    u16* x2b   = (u16*)((char*)d_ws + (size_t)NTOK * 1024 * 2);
    u16* wib   = x2b + (size_t)NTOK * 256;
    u16* wob   = wib + 768 * 256;
    u16* w1b   = wob + 256 * 256;
    u16* w2b   = w1b + 1024 * 256;

    // 1. weights -> bf16  +  xb = LN1(src) -> bf16   (one kernel)
    prep<<<768 + NTOK / 4, 256, 0, stream>>>(
        w_in, wib, w_out, wob, w1, w1b, w2, w2b, src, xb, g1, be1);
    // 2. qb = Q (scaled), kfbuf/vfbuf = K,V fragment-ordered  (= xb @ w_in^T)
    mgemm<256, 128, 0><<<dim3(6, 64), 256, 0, stream>>>(
        xb, wib, (const float*)kfbuf, (const float*)vfbuf, nullptr, qb, 768);
    // 3. attnb = flash-attention(qb, kfbuf, vfbuf)
    attn_k<<<dim3(1024), 256, 0, stream>>>(qb, kfbuf, vfbuf, attnb);
    // 4. out = src + attnb @ w_out^T (fp32)  +  x2b = LN2(out)   (fused)
    g4ln<<<256, 512, 0, stream>>>(attnb, wob, src, out, x2b, g2, be2);
    // 5. h1b = relu(x2b @ w1^T + b1) -> bf16
    mgemm<256, 128, 2><<<dim3(8, 64), 256, 0, stream>>>(
        x2b, w1b, b1, nullptr, nullptr, h1b, 1024);
    // 6. out = out + h1b @ w2^T + b2 (fp32)
    mgemm<1024, 64, 3><<<dim3(4, 128), 256, 0, stream>>>(
        h1b, w2b, b2, out, out, nullptr, 256);
}